// Round 1
// baseline (3517.213 us; speedup 1.0000x reference)
//
#include <hip/hip_runtime.h>

#define DD 128

// ---------------------------------------------------------------------------
// Stage 1: for each (node_idx[i], edge_idx[i]) pair, scatter-add vfeat[node]
// into esum[edge] and bump cnt[edge]. 32 threads per nnz entry, float4 each.
// ---------------------------------------------------------------------------
__global__ __launch_bounds__(256) void k_scatter_edge(
    const float* __restrict__ vfeat,
    const int* __restrict__ node_idx,
    const int* __restrict__ edge_idx,
    float* __restrict__ esum,   // [E][128] (efeat region of d_out), pre-zeroed
    float* __restrict__ cnt,    // [E], pre-zeroed
    int nnz)
{
    int t = blockIdx.x * blockDim.x + threadIdx.x;   // nnz*32 <= 32M < 2^31
    int i = t >> 5;
    if (i >= nnz) return;
    int c = (t & 31) << 2;
    int n = node_idx[i];
    int e = edge_idx[i];
    const float4 v = *(const float4*)(vfeat + (size_t)n * DD + c);
    float* dst = esum + (size_t)e * DD + c;
    atomicAdd(dst + 0, v.x);
    atomicAdd(dst + 1, v.y);
    atomicAdd(dst + 2, v.z);
    atomicAdd(dst + 3, v.w);
    if ((t & 31) == 0) atomicAdd(cnt + e, 1.0f);
}

// ---------------------------------------------------------------------------
// efeat_new = esum / max(cnt, 1)   (in place on the efeat region of d_out)
// ---------------------------------------------------------------------------
__global__ __launch_bounds__(256) void k_normalize_edge(
    float* __restrict__ efeat,
    const float* __restrict__ cnt,
    int n_edges)
{
    int t = blockIdx.x * blockDim.x + threadIdx.x;
    int e = t >> 5;
    if (e >= n_edges) return;
    int c = (t & 31) << 2;
    float inv = 1.0f / fmaxf(cnt[e], 1.0f);
    float4* p = (float4*)(efeat + (size_t)e * DD + c);
    float4 v = *p;
    v.x *= inv; v.y *= inv; v.z *= inv; v.w *= inv;
    *p = v;
}

// ---------------------------------------------------------------------------
// Stage 2: h[node] += degE[edge] * efeat_new[edge]  (atomic scatter into the
// v region of d_out, pre-zeroed). degV multiply is folded into the GEMM.
// ---------------------------------------------------------------------------
__global__ __launch_bounds__(256) void k_scatter_node(
    const float* __restrict__ efeat_new,
    const float* __restrict__ degE,
    const int* __restrict__ node_idx,
    const int* __restrict__ edge_idx,
    float* __restrict__ h,
    int nnz)
{
    int t = blockIdx.x * blockDim.x + threadIdx.x;
    int i = t >> 5;
    if (i >= nnz) return;
    int c = (t & 31) << 2;
    int n = node_idx[i];
    int e = edge_idx[i];
    float w = degE[e];
    const float4 v = *(const float4*)(efeat_new + (size_t)e * DD + c);
    float* dst = h + (size_t)n * DD + c;
    atomicAdd(dst + 0, w * v.x);
    atomicAdd(dst + 1, w * v.y);
    atomicAdd(dst + 2, w * v.z);
    atomicAdd(dst + 3, w * v.w);
}

// ---------------------------------------------------------------------------
// Final fused kernel, in place on the v region of d_out:
//   vi[n][k] = (1-a) * degV[n] * h[n][k] + a * vfeat0[n][k]   (h == vout)
//   v[n][d]  = (1-b) * vi[n][d] + b * sum_k vi[n][k] * W[d][k]
// 64-node tile per block; each block stages its own rows into LDS before
// overwriting them, so in-place is safe (no cross-block row reads).
// ---------------------------------------------------------------------------
__global__ __launch_bounds__(256) void k_fused_gemm(
    float* __restrict__ vout,           // in: h, out: v   [N][128]
    const float* __restrict__ vfeat0,   // [N][128]
    const float* __restrict__ degV,     // [N]
    const float* __restrict__ W,        // [128][128]
    const float* __restrict__ alpha,
    const float* __restrict__ beta,
    int n_nodes)
{
    __shared__ float Al[64][132];    // vi tile, +4 pad
    __shared__ float Wl[128][132];   // full W, +4 pad

    const int tid = threadIdx.x;
    const float a = alpha[0];
    const float b = beta[0];
    const int nb = blockIdx.x * 64;

    // ---- stage W: 128x128 floats, 16 float4 per thread, coalesced ----
    for (int i = tid; i < 128 * 32; i += 256) {
        int row = i >> 5;
        int g = (i & 31) << 2;
        const float4 w4 = *(const float4*)(W + row * 128 + g);
        *(float4*)&Wl[row][g] = w4;
    }

    // ---- stage A = vi tile (fused h/vfeat0/degV/alpha) ----
    {
        const int lx = tid & 31;       // k-chunk index
        const int ly = tid >> 5;       // 0..7
        const int kc = lx << 2;
        const float oma = 1.0f - a;
        #pragma unroll
        for (int it = 0; it < 8; ++it) {
            int ln = ly + it * 8;      // 0..63
            int n = nb + ln;
            float4 v;
            if (n < n_nodes) {
                float s = oma * degV[n];
                const float4 h4 = *(const float4*)(vout + (size_t)n * DD + kc);
                const float4 f4 = *(const float4*)(vfeat0 + (size_t)n * DD + kc);
                v.x = s * h4.x + a * f4.x;
                v.y = s * h4.y + a * f4.y;
                v.z = s * h4.z + a * f4.z;
                v.w = s * h4.w + a * f4.w;
            } else {
                v.x = v.y = v.z = v.w = 0.0f;
            }
            *(float4*)&Al[ln][kc] = v;
        }
    }
    __syncthreads();

    // ---- register-tiled GEMM: thread (ty,tx) -> rows ty*8+i, cols tx+32*j ----
    const int tx = tid & 31;
    const int ty = tid >> 5;

    float acc[8][4];
    #pragma unroll
    for (int i = 0; i < 8; ++i)
        #pragma unroll
        for (int j = 0; j < 4; ++j) acc[i][j] = 0.0f;

    for (int kc = 0; kc < 32; ++kc) {
        const int k4 = kc << 2;
        float4 af[8];
        #pragma unroll
        for (int i = 0; i < 8; ++i) af[i] = *(const float4*)&Al[ty * 8 + i][k4];
        float4 bf[4];
        #pragma unroll
        for (int j = 0; j < 4; ++j) bf[j] = *(const float4*)&Wl[tx + 32 * j][k4];
        #pragma unroll
        for (int i = 0; i < 8; ++i) {
            #pragma unroll
            for (int j = 0; j < 4; ++j) {
                acc[i][j] += af[i].x * bf[j].x;
                acc[i][j] += af[i].y * bf[j].y;
                acc[i][j] += af[i].z * bf[j].z;
                acc[i][j] += af[i].w * bf[j].w;
            }
        }
    }

    // ---- epilogue: v = (1-b)*vi + b*acc ----
    const float omb = 1.0f - b;
    #pragma unroll
    for (int i = 0; i < 8; ++i) {
        int ln = ty * 8 + i;
        int n = nb + ln;
        if (n < n_nodes) {
            #pragma unroll
            for (int j = 0; j < 4; ++j) {
                int c = tx + 32 * j;
                vout[(size_t)n * DD + c] = omb * Al[ln][c] + b * acc[i][j];
            }
        }
    }
}

// ---------------------------------------------------------------------------
extern "C" void kernel_launch(void* const* d_in, const int* in_sizes, int n_in,
                              void* d_out, int out_size, void* d_ws, size_t ws_size,
                              hipStream_t stream)
{
    const float* vfeat  = (const float*)d_in[0];
    // d_in[1] (efeat) is unused: the layer overwrites it.
    const float* degE   = (const float*)d_in[2];
    const float* degV   = (const float*)d_in[3];
    const float* vfeat0 = (const float*)d_in[4];
    const float* W      = (const float*)d_in[5];
    const float* alpha  = (const float*)d_in[6];
    const float* beta   = (const float*)d_in[7];
    const int* node_idx = (const int*)d_in[8];
    const int* edge_idx = (const int*)d_in[9];

    const int E   = in_sizes[2];
    const int N   = in_sizes[3];
    const int NNZ = in_sizes[8];

    float* vout  = (float*)d_out;                 // [N][128]: h accumulator, then v
    float* eout  = (float*)d_out + (size_t)N * DD; // [E][128]: esum, then efeat_new
    float* cnt   = (float*)d_ws;                   // [E]

    // Zero accumulators (harness poisons once; we must re-init every call).
    hipMemsetAsync(d_out, 0, (size_t)out_size * sizeof(float), stream);
    hipMemsetAsync(cnt, 0, (size_t)E * sizeof(float), stream);

    // Stage 1: node -> edge mean
    {
        int threads = NNZ * 32;
        int blocks = (threads + 255) / 256;
        k_scatter_edge<<<blocks, 256, 0, stream>>>(vfeat, node_idx, edge_idx,
                                                   eout, cnt, NNZ);
    }
    {
        int threads = E * 32;
        int blocks = (threads + 255) / 256;
        k_normalize_edge<<<blocks, 256, 0, stream>>>(eout, cnt, E);
    }

    // Stage 2: edge -> node weighted sum (h into vout)
    {
        int threads = NNZ * 32;
        int blocks = (threads + 255) / 256;
        k_scatter_node<<<blocks, 256, 0, stream>>>(eout, degE, node_idx, edge_idx,
                                                   vout, NNZ);
    }

    // Final: vi + GCNII linear, in place on vout
    {
        int blocks = (N + 63) / 64;
        k_fused_gemm<<<blocks, 256, 0, stream>>>(vout, vfeat0, degV, W,
                                                 alpha, beta, N);
    }
}

// Round 2
// 533.020 us; speedup vs baseline: 6.5987x; 6.5987x over previous
//
#include <hip/hip_runtime.h>

#define DD 128

// ===========================================================================
// CSR-gather implementation (primary path)
// ===========================================================================

// ---- histogram: count incidences per edge and per node --------------------
__global__ __launch_bounds__(256) void k_hist(
    const int* __restrict__ node_idx,
    const int* __restrict__ edge_idx,
    int* __restrict__ countE,
    int* __restrict__ countV,
    int nnz)
{
    int i = blockIdx.x * blockDim.x + threadIdx.x;
    if (i >= nnz) return;
    atomicAdd(&countE[edge_idx[i]], 1);
    atomicAdd(&countV[node_idx[i]], 1);
}

// ---- hierarchical exclusive scan, chunk = 4096 ----------------------------
__global__ __launch_bounds__(256) void k_chunk_sums(
    const int* __restrict__ cnt, int L, int* __restrict__ partials)
{
    __shared__ int red[256];
    const int tid = threadIdx.x;
    const int base = blockIdx.x * 4096;
    int s = 0;
    for (int j = tid; j < 4096; j += 256) {
        int i = base + j;
        s += (i < L) ? cnt[i] : 0;
    }
    red[tid] = s;
    __syncthreads();
    for (int off = 128; off > 0; off >>= 1) {
        if (tid < off) red[tid] += red[tid + off];
        __syncthreads();
    }
    if (tid == 0) partials[blockIdx.x] = red[0];
}

__global__ void k_scan_partials(int* __restrict__ partials, int nb,
                                int* __restrict__ total_out)
{
    if (threadIdx.x == 0) {
        int run = 0;
        for (int b = 0; b < nb; ++b) {
            int t = partials[b];
            partials[b] = run;
            run += t;
        }
        *total_out = run;
    }
}

__global__ __launch_bounds__(256) void k_scan_chunks(
    const int* __restrict__ cnt, int L,
    const int* __restrict__ partials, int* __restrict__ rowptr)
{
    __shared__ int tsum[256];
    const int tid = threadIdx.x;
    const int tbase = blockIdx.x * 4096 + tid * 16;
    int loc[16];
    int s = 0;
    #pragma unroll
    for (int k = 0; k < 16; ++k) {
        int i = tbase + k;
        loc[k] = (i < L) ? cnt[i] : 0;
        s += loc[k];
    }
    tsum[tid] = s;
    __syncthreads();
    if (tid == 0) {
        int run = partials[blockIdx.x];
        for (int j = 0; j < 256; ++j) {
            int t = tsum[j];
            tsum[j] = run;
            run += t;
        }
    }
    __syncthreads();
    int run = tsum[tid];
    #pragma unroll
    for (int k = 0; k < 16; ++k) {
        int i = tbase + k;
        if (i < L) rowptr[i] = run;
        run += loc[k];
    }
}

// ---- fill adjacency lists -------------------------------------------------
__global__ __launch_bounds__(256) void k_fill(
    const int* __restrict__ node_idx,
    const int* __restrict__ edge_idx,
    int* __restrict__ cursorE, int* __restrict__ cursorV,
    int* __restrict__ adjE, int* __restrict__ adjV,
    int nnz)
{
    int i = blockIdx.x * blockDim.x + threadIdx.x;
    if (i >= nnz) return;
    int n = node_idx[i];
    int e = edge_idx[i];
    int pE = atomicAdd(&cursorE[e], 1);
    adjE[pE] = n;
    int pV = atomicAdd(&cursorV[n], 1);
    adjV[pV] = e;
}

// ---- stage 1 gather: efeat_new[e] = mean over incident nodes of vfeat -----
__global__ __launch_bounds__(128) void k_gather_edge(
    const float* __restrict__ vfeat,
    const int* __restrict__ rowptrE,
    const int* __restrict__ adjE,
    float* __restrict__ efeat,
    int n_edges)
{
    const int e = blockIdx.x;
    const int c = threadIdx.x;
    const int beg = rowptrE[e];
    const int len = rowptrE[e + 1] - beg;

    __shared__ int nid[128];
    float a0 = 0.f, a1 = 0.f, a2 = 0.f, a3 = 0.f;

    for (int base = 0; base < len; base += 128) {
        int j = base + c;
        nid[c] = (j < len) ? adjE[beg + j] : 0;
        __syncthreads();
        int m = min(128, len - base);
        int k = 0;
        for (; k + 3 < m; k += 4) {
            a0 += vfeat[(size_t)nid[k + 0] * DD + c];
            a1 += vfeat[(size_t)nid[k + 1] * DD + c];
            a2 += vfeat[(size_t)nid[k + 2] * DD + c];
            a3 += vfeat[(size_t)nid[k + 3] * DD + c];
        }
        for (; k < m; ++k) a0 += vfeat[(size_t)nid[k] * DD + c];
        __syncthreads();
    }
    float inv = (len > 0) ? 1.0f / (float)len : 0.0f;
    efeat[(size_t)e * DD + c] = (a0 + a1 + a2 + a3) * inv;
}

// ---- stage 2 gather: h[n] = sum over incident edges of degE[e]*efeat[e] ---
__global__ __launch_bounds__(128) void k_gather_node(
    const float* __restrict__ efeat,
    const float* __restrict__ degE,
    const int* __restrict__ rowptrV,
    const int* __restrict__ adjV,
    float* __restrict__ h,
    int n_nodes)
{
    const int n = blockIdx.x;
    const int c = threadIdx.x;
    const int beg = rowptrV[n];
    const int len = rowptrV[n + 1] - beg;

    __shared__ int eid[128];
    __shared__ float ew[128];
    float a0 = 0.f, a1 = 0.f, a2 = 0.f, a3 = 0.f;

    for (int base = 0; base < len; base += 128) {
        int j = base + c;
        int e = (j < len) ? adjV[beg + j] : 0;
        eid[c] = e;
        ew[c] = (j < len) ? degE[e] : 0.0f;
        __syncthreads();
        int m = min(128, len - base);
        int k = 0;
        for (; k + 3 < m; k += 4) {
            a0 += ew[k + 0] * efeat[(size_t)eid[k + 0] * DD + c];
            a1 += ew[k + 1] * efeat[(size_t)eid[k + 1] * DD + c];
            a2 += ew[k + 2] * efeat[(size_t)eid[k + 2] * DD + c];
            a3 += ew[k + 3] * efeat[(size_t)eid[k + 3] * DD + c];
        }
        for (; k < m; ++k) a0 += ew[k] * efeat[(size_t)eid[k] * DD + c];
        __syncthreads();
    }
    h[(size_t)n * DD + c] = a0 + a1 + a2 + a3;
}

// ---------------------------------------------------------------------------
// Final fused kernel, in place on the v region of d_out:
//   vi[n][k] = (1-a) * degV[n] * h[n][k] + a * vfeat0[n][k]   (h == vout)
//   v[n][d]  = (1-b) * vi[n][d] + b * sum_k vi[n][k] * W[d][k]
// ---------------------------------------------------------------------------
__global__ __launch_bounds__(256) void k_fused_gemm(
    float* __restrict__ vout,
    const float* __restrict__ vfeat0,
    const float* __restrict__ degV,
    const float* __restrict__ W,
    const float* __restrict__ alpha,
    const float* __restrict__ beta,
    int n_nodes)
{
    __shared__ float Al[64][132];
    __shared__ float Wl[128][132];

    const int tid = threadIdx.x;
    const float a = alpha[0];
    const float b = beta[0];
    const int nb = blockIdx.x * 64;

    for (int i = tid; i < 128 * 32; i += 256) {
        int row = i >> 5;
        int g = (i & 31) << 2;
        *(float4*)&Wl[row][g] = *(const float4*)(W + row * 128 + g);
    }

    {
        const int lx = tid & 31;
        const int ly = tid >> 5;
        const int kc = lx << 2;
        const float oma = 1.0f - a;
        #pragma unroll
        for (int it = 0; it < 8; ++it) {
            int ln = ly + it * 8;
            int n = nb + ln;
            float4 v;
            if (n < n_nodes) {
                float s = oma * degV[n];
                const float4 h4 = *(const float4*)(vout + (size_t)n * DD + kc);
                const float4 f4 = *(const float4*)(vfeat0 + (size_t)n * DD + kc);
                v.x = s * h4.x + a * f4.x;
                v.y = s * h4.y + a * f4.y;
                v.z = s * h4.z + a * f4.z;
                v.w = s * h4.w + a * f4.w;
            } else {
                v.x = v.y = v.z = v.w = 0.0f;
            }
            *(float4*)&Al[ln][kc] = v;
        }
    }
    __syncthreads();

    const int tx = tid & 31;
    const int ty = tid >> 5;

    float acc[8][4];
    #pragma unroll
    for (int i = 0; i < 8; ++i)
        #pragma unroll
        for (int j = 0; j < 4; ++j) acc[i][j] = 0.0f;

    for (int kc = 0; kc < 32; ++kc) {
        const int k4 = kc << 2;
        float4 af[8];
        #pragma unroll
        for (int i = 0; i < 8; ++i) af[i] = *(const float4*)&Al[ty * 8 + i][k4];
        float4 bf[4];
        #pragma unroll
        for (int j = 0; j < 4; ++j) bf[j] = *(const float4*)&Wl[tx + 32 * j][k4];
        #pragma unroll
        for (int i = 0; i < 8; ++i) {
            #pragma unroll
            for (int j = 0; j < 4; ++j) {
                acc[i][j] += af[i].x * bf[j].x;
                acc[i][j] += af[i].y * bf[j].y;
                acc[i][j] += af[i].z * bf[j].z;
                acc[i][j] += af[i].w * bf[j].w;
            }
        }
    }

    const float omb = 1.0f - b;
    #pragma unroll
    for (int i = 0; i < 8; ++i) {
        int ln = ty * 8 + i;
        int n = nb + ln;
        if (n < n_nodes) {
            #pragma unroll
            for (int j = 0; j < 4; ++j) {
                int c = tx + 32 * j;
                vout[(size_t)n * DD + c] = omb * Al[ln][c] + b * acc[i][j];
            }
        }
    }
}

// ===========================================================================
// Fallback atomic-scatter kernels (used only if ws_size too small)
// ===========================================================================
__global__ __launch_bounds__(256) void k_scatter_edge(
    const float* __restrict__ vfeat, const int* __restrict__ node_idx,
    const int* __restrict__ edge_idx, float* __restrict__ esum,
    float* __restrict__ cnt, int nnz)
{
    int t = blockIdx.x * blockDim.x + threadIdx.x;
    int i = t >> 5;
    if (i >= nnz) return;
    int c = (t & 31) << 2;
    int n = node_idx[i];
    int e = edge_idx[i];
    const float4 v = *(const float4*)(vfeat + (size_t)n * DD + c);
    float* dst = esum + (size_t)e * DD + c;
    atomicAdd(dst + 0, v.x); atomicAdd(dst + 1, v.y);
    atomicAdd(dst + 2, v.z); atomicAdd(dst + 3, v.w);
    if ((t & 31) == 0) atomicAdd(cnt + e, 1.0f);
}

__global__ __launch_bounds__(256) void k_normalize_edge(
    float* __restrict__ efeat, const float* __restrict__ cnt, int n_edges)
{
    int t = blockIdx.x * blockDim.x + threadIdx.x;
    int e = t >> 5;
    if (e >= n_edges) return;
    int c = (t & 31) << 2;
    float inv = 1.0f / fmaxf(cnt[e], 1.0f);
    float4* p = (float4*)(efeat + (size_t)e * DD + c);
    float4 v = *p;
    v.x *= inv; v.y *= inv; v.z *= inv; v.w *= inv;
    *p = v;
}

__global__ __launch_bounds__(256) void k_scatter_node(
    const float* __restrict__ efeat_new, const float* __restrict__ degE,
    const int* __restrict__ node_idx, const int* __restrict__ edge_idx,
    float* __restrict__ h, int nnz)
{
    int t = blockIdx.x * blockDim.x + threadIdx.x;
    int i = t >> 5;
    if (i >= nnz) return;
    int c = (t & 31) << 2;
    int n = node_idx[i];
    int e = edge_idx[i];
    float w = degE[e];
    const float4 v = *(const float4*)(efeat_new + (size_t)e * DD + c);
    float* dst = h + (size_t)n * DD + c;
    atomicAdd(dst + 0, w * v.x); atomicAdd(dst + 1, w * v.y);
    atomicAdd(dst + 2, w * v.z); atomicAdd(dst + 3, w * v.w);
}

// ===========================================================================
extern "C" void kernel_launch(void* const* d_in, const int* in_sizes, int n_in,
                              void* d_out, int out_size, void* d_ws, size_t ws_size,
                              hipStream_t stream)
{
    const float* vfeat  = (const float*)d_in[0];
    const float* degE   = (const float*)d_in[2];
    const float* degV   = (const float*)d_in[3];
    const float* vfeat0 = (const float*)d_in[4];
    const float* W      = (const float*)d_in[5];
    const float* alpha  = (const float*)d_in[6];
    const float* beta   = (const float*)d_in[7];
    const int* node_idx = (const int*)d_in[8];
    const int* edge_idx = (const int*)d_in[9];

    const int E   = in_sizes[2];
    const int N   = in_sizes[3];
    const int NNZ = in_sizes[8];

    float* vout = (float*)d_out;                   // [N][128]
    float* eout = (float*)d_out + (size_t)N * DD;  // [E][128]

    // workspace layout (ints)
    const size_t need = ((size_t)3 * E + 3 * N + 2 * (size_t)NNZ + 130) * sizeof(int);

    if (ws_size >= need) {
        int* countE  = (int*)d_ws;            // E
        int* countV  = countE + E;            // N
        int* rowptrE = countV + N;            // E+1
        int* rowptrV = rowptrE + E + 1;       // N+1
        int* cursorE = rowptrV + N + 1;       // E
        int* cursorV = cursorE + E;           // N
        int* partE   = cursorV + N;           // 64
        int* partV   = partE + 64;            // 64
        int* adjE    = partV + 64;            // NNZ
        int* adjV    = adjE + NNZ;            // NNZ

        const int nbE = (E + 4095) / 4096;
        const int nbV = (N + 4095) / 4096;

        hipMemsetAsync(countE, 0, (size_t)(E + N) * sizeof(int), stream);

        k_hist<<<(NNZ + 255) / 256, 256, 0, stream>>>(node_idx, edge_idx,
                                                      countE, countV, NNZ);
        k_chunk_sums<<<nbE, 256, 0, stream>>>(countE, E, partE);
        k_chunk_sums<<<nbV, 256, 0, stream>>>(countV, N, partV);
        k_scan_partials<<<1, 64, 0, stream>>>(partE, nbE, rowptrE + E);
        k_scan_partials<<<1, 64, 0, stream>>>(partV, nbV, rowptrV + N);
        k_scan_chunks<<<nbE, 256, 0, stream>>>(countE, E, partE, rowptrE);
        k_scan_chunks<<<nbV, 256, 0, stream>>>(countV, N, partV, rowptrV);

        hipMemcpyAsync(cursorE, rowptrE, (size_t)E * sizeof(int),
                       hipMemcpyDeviceToDevice, stream);
        hipMemcpyAsync(cursorV, rowptrV, (size_t)N * sizeof(int),
                       hipMemcpyDeviceToDevice, stream);

        k_fill<<<(NNZ + 255) / 256, 256, 0, stream>>>(node_idx, edge_idx,
                                                      cursorE, cursorV,
                                                      adjE, adjV, NNZ);

        k_gather_edge<<<E, 128, 0, stream>>>(vfeat, rowptrE, adjE, eout, E);
        k_gather_node<<<N, 128, 0, stream>>>(eout, degE, rowptrV, adjV, vout, N);
        k_fused_gemm<<<(N + 63) / 64, 256, 0, stream>>>(vout, vfeat0, degV, W,
                                                        alpha, beta, N);
    } else {
        // fallback: atomic scatter path
        float* cnt = (float*)d_ws;
        hipMemsetAsync(d_out, 0, (size_t)out_size * sizeof(float), stream);
        hipMemsetAsync(cnt, 0, (size_t)E * sizeof(float), stream);
        {
            long long threads = (long long)NNZ * 32;
            int blocks = (int)((threads + 255) / 256);
            k_scatter_edge<<<blocks, 256, 0, stream>>>(vfeat, node_idx, edge_idx,
                                                       eout, cnt, NNZ);
        }
        {
            int blocks = (E * 32 + 255) / 256;
            k_normalize_edge<<<blocks, 256, 0, stream>>>(eout, cnt, E);
        }
        {
            long long threads = (long long)NNZ * 32;
            int blocks = (int)((threads + 255) / 256);
            k_scatter_node<<<blocks, 256, 0, stream>>>(eout, degE, node_idx, edge_idx,
                                                       vout, NNZ);
        }
        k_fused_gemm<<<(N + 63) / 64, 256, 0, stream>>>(vout, vfeat0, degV, W,
                                                        alpha, beta, N);
    }
}

// Round 3
// 444.323 us; speedup vs baseline: 7.9159x; 1.1996x over previous
//
#include <hip/hip_runtime.h>

#define DD 128
#define NSLICE 8

// ===========================================================================
// CSR build
// ===========================================================================

// ---- histogram: count incidences per edge and per node --------------------
__global__ __launch_bounds__(256) void k_hist(
    const int* __restrict__ node_idx,
    const int* __restrict__ edge_idx,
    int* __restrict__ countE,
    int* __restrict__ countV,
    int nnz)
{
    int i = blockIdx.x * blockDim.x + threadIdx.x;
    if (i >= nnz) return;
    atomicAdd(&countE[edge_idx[i]], 1);
    atomicAdd(&countV[node_idx[i]], 1);
}

// ---- hierarchical exclusive scan, chunk = 4096 ----------------------------
__global__ __launch_bounds__(256) void k_chunk_sums(
    const int* __restrict__ cnt, int L, int* __restrict__ partials)
{
    __shared__ int red[256];
    const int tid = threadIdx.x;
    const int base = blockIdx.x * 4096;
    int s = 0;
    for (int j = tid; j < 4096; j += 256) {
        int i = base + j;
        s += (i < L) ? cnt[i] : 0;
    }
    red[tid] = s;
    __syncthreads();
    for (int off = 128; off > 0; off >>= 1) {
        if (tid < off) red[tid] += red[tid + off];
        __syncthreads();
    }
    if (tid == 0) partials[blockIdx.x] = red[0];
}

// scan both partial arrays in one dispatch (block 0: E, block 1: V)
__global__ void k_scan_partials2(int* __restrict__ pE, int nbE, int* __restrict__ totE,
                                 int* __restrict__ pV, int nbV, int* __restrict__ totV)
{
    if (threadIdx.x != 0) return;
    int* p = (blockIdx.x == 0) ? pE : pV;
    int  nb = (blockIdx.x == 0) ? nbE : nbV;
    int* tot = (blockIdx.x == 0) ? totE : totV;
    int run = 0;
    for (int b = 0; b < nb; ++b) {
        int t = p[b];
        p[b] = run;
        run += t;
    }
    *tot = run;
}

// writes rowptr AND initializes cursor = rowptr in the same pass
__global__ __launch_bounds__(256) void k_scan_chunks(
    const int* __restrict__ cnt, int L,
    const int* __restrict__ partials,
    int* __restrict__ rowptr, int* __restrict__ cursor)
{
    __shared__ int tsum[256];
    const int tid = threadIdx.x;
    const int tbase = blockIdx.x * 4096 + tid * 16;
    int loc[16];
    int s = 0;
    #pragma unroll
    for (int k = 0; k < 16; ++k) {
        int i = tbase + k;
        loc[k] = (i < L) ? cnt[i] : 0;
        s += loc[k];
    }
    tsum[tid] = s;
    __syncthreads();
    if (tid == 0) {
        int run = partials[blockIdx.x];
        for (int j = 0; j < 256; ++j) {
            int t = tsum[j];
            tsum[j] = run;
            run += t;
        }
    }
    __syncthreads();
    int run = tsum[tid];
    #pragma unroll
    for (int k = 0; k < 16; ++k) {
        int i = tbase + k;
        if (i < L) { rowptr[i] = run; cursor[i] = run; }
        run += loc[k];
    }
}

// ---- XCD-sliced adjacency fill ---------------------------------------------
// Slice s = blockIdx % 8 maps (round-robin dispatch) to one XCD. Each slice
// group scans ALL pairs but only writes adjacency slots whose edge/node falls
// in its 1/8 range -> each output line is dirtied by a single XCD's L2 and
// written back once as a full line (kills the 16x write amplification).
__global__ __launch_bounds__(256) void k_fill_sliced(
    const int* __restrict__ node_idx,
    const int* __restrict__ edge_idx,
    int* __restrict__ cursorE, int* __restrict__ cursorV,
    int* __restrict__ adjE, int* __restrict__ adjV,
    int nnz, int E, int N)
{
    const int s = blockIdx.x & (NSLICE - 1);
    const int g = blockIdx.x >> 3;
    const int ngroups = gridDim.x >> 3;
    const int eb = (E + NSLICE - 1) / NSLICE;
    const int nb = (N + NSLICE - 1) / NSLICE;
    const int elo = s * eb, ehi = min(E, elo + eb);
    const int nlo = s * nb, nhi = min(N, nlo + nb);

    const int stride = ngroups * 256;
    for (int i = g * 256 + threadIdx.x; i < nnz; i += stride) {
        int n = node_idx[i];
        int e = edge_idx[i];
        if (e >= elo && e < ehi) {
            int p = atomicAdd(&cursorE[e], 1);
            adjE[p] = n;
        }
        if (n >= nlo && n < nhi) {
            int p = atomicAdd(&cursorV[n], 1);
            adjV[p] = e;
        }
    }
}

// ===========================================================================
// Gather stages: one 32-lane group per output row, float4 per lane.
// ===========================================================================

// ---- stage 1: efeat_new[e] = mean over incident nodes of vfeat ------------
__global__ __launch_bounds__(256) void k_gather_edge(
    const float* __restrict__ vfeat,
    const int* __restrict__ rowptrE,
    const int* __restrict__ adjE,
    float* __restrict__ efeat,
    int n_edges)
{
    const int gid = (blockIdx.x * blockDim.x + threadIdx.x) >> 5;
    if (gid >= n_edges) return;
    const int lane = threadIdx.x & 31;
    const int beg = rowptrE[gid];
    const int len = rowptrE[gid + 1] - beg;

    const float* vb = vfeat + (size_t)lane * 4;
    float4 c0 = {0,0,0,0}, c1 = {0,0,0,0}, c2 = {0,0,0,0}, c3 = {0,0,0,0};

    int k = 0;
    for (; k + 4 <= len; k += 4) {
        int e0 = adjE[beg + k + 0];
        int e1 = adjE[beg + k + 1];
        int e2 = adjE[beg + k + 2];
        int e3 = adjE[beg + k + 3];
        float4 r0 = *(const float4*)(vb + (size_t)e0 * DD);
        float4 r1 = *(const float4*)(vb + (size_t)e1 * DD);
        float4 r2 = *(const float4*)(vb + (size_t)e2 * DD);
        float4 r3 = *(const float4*)(vb + (size_t)e3 * DD);
        c0.x += r0.x; c0.y += r0.y; c0.z += r0.z; c0.w += r0.w;
        c1.x += r1.x; c1.y += r1.y; c1.z += r1.z; c1.w += r1.w;
        c2.x += r2.x; c2.y += r2.y; c2.z += r2.z; c2.w += r2.w;
        c3.x += r3.x; c3.y += r3.y; c3.z += r3.z; c3.w += r3.w;
    }
    for (; k < len; ++k) {
        int e0 = adjE[beg + k];
        float4 r0 = *(const float4*)(vb + (size_t)e0 * DD);
        c0.x += r0.x; c0.y += r0.y; c0.z += r0.z; c0.w += r0.w;
    }
    float inv = (len > 0) ? 1.0f / (float)len : 0.0f;
    float4 o;
    o.x = (c0.x + c1.x + c2.x + c3.x) * inv;
    o.y = (c0.y + c1.y + c2.y + c3.y) * inv;
    o.z = (c0.z + c1.z + c2.z + c3.z) * inv;
    o.w = (c0.w + c1.w + c2.w + c3.w) * inv;
    *(float4*)(efeat + (size_t)gid * DD + lane * 4) = o;
}

// ---- stage 2: h[n] = sum over incident edges of degE[e]*efeat[e] ----------
__global__ __launch_bounds__(256) void k_gather_node(
    const float* __restrict__ efeat,
    const float* __restrict__ degE,
    const int* __restrict__ rowptrV,
    const int* __restrict__ adjV,
    float* __restrict__ h,
    int n_nodes)
{
    const int gid = (blockIdx.x * blockDim.x + threadIdx.x) >> 5;
    if (gid >= n_nodes) return;
    const int lane = threadIdx.x & 31;
    const int beg = rowptrV[gid];
    const int len = rowptrV[gid + 1] - beg;

    const float* eb = efeat + (size_t)lane * 4;
    float4 c0 = {0,0,0,0}, c1 = {0,0,0,0}, c2 = {0,0,0,0}, c3 = {0,0,0,0};

    int k = 0;
    for (; k + 4 <= len; k += 4) {
        int e0 = adjV[beg + k + 0];
        int e1 = adjV[beg + k + 1];
        int e2 = adjV[beg + k + 2];
        int e3 = adjV[beg + k + 3];
        float w0 = degE[e0], w1 = degE[e1], w2 = degE[e2], w3 = degE[e3];
        float4 r0 = *(const float4*)(eb + (size_t)e0 * DD);
        float4 r1 = *(const float4*)(eb + (size_t)e1 * DD);
        float4 r2 = *(const float4*)(eb + (size_t)e2 * DD);
        float4 r3 = *(const float4*)(eb + (size_t)e3 * DD);
        c0.x += w0 * r0.x; c0.y += w0 * r0.y; c0.z += w0 * r0.z; c0.w += w0 * r0.w;
        c1.x += w1 * r1.x; c1.y += w1 * r1.y; c1.z += w1 * r1.z; c1.w += w1 * r1.w;
        c2.x += w2 * r2.x; c2.y += w2 * r2.y; c2.z += w2 * r2.z; c2.w += w2 * r2.w;
        c3.x += w3 * r3.x; c3.y += w3 * r3.y; c3.z += w3 * r3.z; c3.w += w3 * r3.w;
    }
    for (; k < len; ++k) {
        int e0 = adjV[beg + k];
        float w0 = degE[e0];
        float4 r0 = *(const float4*)(eb + (size_t)e0 * DD);
        c0.x += w0 * r0.x; c0.y += w0 * r0.y; c0.z += w0 * r0.z; c0.w += w0 * r0.w;
    }
    float4 o;
    o.x = c0.x + c1.x + c2.x + c3.x;
    o.y = c0.y + c1.y + c2.y + c3.y;
    o.z = c0.z + c1.z + c2.z + c3.z;
    o.w = c0.w + c1.w + c2.w + c3.w;
    *(float4*)(h + (size_t)gid * DD + lane * 4) = o;
}

// ---------------------------------------------------------------------------
// Final fused kernel, in place on the v region of d_out:
//   vi[n][k] = (1-a) * degV[n] * h[n][k] + a * vfeat0[n][k]   (h == vout)
//   v[n][d]  = (1-b) * vi[n][d] + b * sum_k vi[n][k] * W[d][k]
// ---------------------------------------------------------------------------
__global__ __launch_bounds__(256) void k_fused_gemm(
    float* __restrict__ vout,
    const float* __restrict__ vfeat0,
    const float* __restrict__ degV,
    const float* __restrict__ W,
    const float* __restrict__ alpha,
    const float* __restrict__ beta,
    int n_nodes)
{
    __shared__ float Al[64][132];
    __shared__ float Wl[128][132];

    const int tid = threadIdx.x;
    const float a = alpha[0];
    const float b = beta[0];
    const int nb = blockIdx.x * 64;

    for (int i = tid; i < 128 * 32; i += 256) {
        int row = i >> 5;
        int g = (i & 31) << 2;
        *(float4*)&Wl[row][g] = *(const float4*)(W + row * 128 + g);
    }

    {
        const int lx = tid & 31;
        const int ly = tid >> 5;
        const int kc = lx << 2;
        const float oma = 1.0f - a;
        #pragma unroll
        for (int it = 0; it < 8; ++it) {
            int ln = ly + it * 8;
            int n = nb + ln;
            float4 v;
            if (n < n_nodes) {
                float s = oma * degV[n];
                const float4 h4 = *(const float4*)(vout + (size_t)n * DD + kc);
                const float4 f4 = *(const float4*)(vfeat0 + (size_t)n * DD + kc);
                v.x = s * h4.x + a * f4.x;
                v.y = s * h4.y + a * f4.y;
                v.z = s * h4.z + a * f4.z;
                v.w = s * h4.w + a * f4.w;
            } else {
                v.x = v.y = v.z = v.w = 0.0f;
            }
            *(float4*)&Al[ln][kc] = v;
        }
    }
    __syncthreads();

    const int tx = tid & 31;
    const int ty = tid >> 5;

    float acc[8][4];
    #pragma unroll
    for (int i = 0; i < 8; ++i)
        #pragma unroll
        for (int j = 0; j < 4; ++j) acc[i][j] = 0.0f;

    for (int kc = 0; kc < 32; ++kc) {
        const int k4 = kc << 2;
        float4 af[8];
        #pragma unroll
        for (int i = 0; i < 8; ++i) af[i] = *(const float4*)&Al[ty * 8 + i][k4];
        float4 bf[4];
        #pragma unroll
        for (int j = 0; j < 4; ++j) bf[j] = *(const float4*)&Wl[tx + 32 * j][k4];
        #pragma unroll
        for (int i = 0; i < 8; ++i) {
            #pragma unroll
            for (int j = 0; j < 4; ++j) {
                acc[i][j] += af[i].x * bf[j].x;
                acc[i][j] += af[i].y * bf[j].y;
                acc[i][j] += af[i].z * bf[j].z;
                acc[i][j] += af[i].w * bf[j].w;
            }
        }
    }

    const float omb = 1.0f - b;
    #pragma unroll
    for (int i = 0; i < 8; ++i) {
        int ln = ty * 8 + i;
        int n = nb + ln;
        if (n < n_nodes) {
            #pragma unroll
            for (int j = 0; j < 4; ++j) {
                int c = tx + 32 * j;
                vout[(size_t)n * DD + c] = omb * Al[ln][c] + b * acc[i][j];
            }
        }
    }
}

// ===========================================================================
// Fallback atomic-scatter kernels (used only if ws_size too small)
// ===========================================================================
__global__ __launch_bounds__(256) void k_scatter_edge(
    const float* __restrict__ vfeat, const int* __restrict__ node_idx,
    const int* __restrict__ edge_idx, float* __restrict__ esum,
    float* __restrict__ cnt, int nnz)
{
    int t = blockIdx.x * blockDim.x + threadIdx.x;
    int i = t >> 5;
    if (i >= nnz) return;
    int c = (t & 31) << 2;
    int n = node_idx[i];
    int e = edge_idx[i];
    const float4 v = *(const float4*)(vfeat + (size_t)n * DD + c);
    float* dst = esum + (size_t)e * DD + c;
    atomicAdd(dst + 0, v.x); atomicAdd(dst + 1, v.y);
    atomicAdd(dst + 2, v.z); atomicAdd(dst + 3, v.w);
    if ((t & 31) == 0) atomicAdd(cnt + e, 1.0f);
}

__global__ __launch_bounds__(256) void k_normalize_edge(
    float* __restrict__ efeat, const float* __restrict__ cnt, int n_edges)
{
    int t = blockIdx.x * blockDim.x + threadIdx.x;
    int e = t >> 5;
    if (e >= n_edges) return;
    int c = (t & 31) << 2;
    float inv = 1.0f / fmaxf(cnt[e], 1.0f);
    float4* p = (float4*)(efeat + (size_t)e * DD + c);
    float4 v = *p;
    v.x *= inv; v.y *= inv; v.z *= inv; v.w *= inv;
    *p = v;
}

__global__ __launch_bounds__(256) void k_scatter_node(
    const float* __restrict__ efeat_new, const float* __restrict__ degE,
    const int* __restrict__ node_idx, const int* __restrict__ edge_idx,
    float* __restrict__ h, int nnz)
{
    int t = blockIdx.x * blockDim.x + threadIdx.x;
    int i = t >> 5;
    if (i >= nnz) return;
    int c = (t & 31) << 2;
    int n = node_idx[i];
    int e = edge_idx[i];
    float w = degE[e];
    const float4 v = *(const float4*)(efeat_new + (size_t)e * DD + c);
    float* dst = h + (size_t)n * DD + c;
    atomicAdd(dst + 0, w * v.x); atomicAdd(dst + 1, w * v.y);
    atomicAdd(dst + 2, w * v.z); atomicAdd(dst + 3, w * v.w);
}

// ===========================================================================
extern "C" void kernel_launch(void* const* d_in, const int* in_sizes, int n_in,
                              void* d_out, int out_size, void* d_ws, size_t ws_size,
                              hipStream_t stream)
{
    const float* vfeat  = (const float*)d_in[0];
    const float* degE   = (const float*)d_in[2];
    const float* degV   = (const float*)d_in[3];
    const float* vfeat0 = (const float*)d_in[4];
    const float* W      = (const float*)d_in[5];
    const float* alpha  = (const float*)d_in[6];
    const float* beta   = (const float*)d_in[7];
    const int* node_idx = (const int*)d_in[8];
    const int* edge_idx = (const int*)d_in[9];

    const int E   = in_sizes[2];
    const int N   = in_sizes[3];
    const int NNZ = in_sizes[8];

    float* vout = (float*)d_out;                   // [N][128]
    float* eout = (float*)d_out + (size_t)N * DD;  // [E][128]

    const size_t need = ((size_t)3 * E + 3 * N + 2 * (size_t)NNZ + 130) * sizeof(int);

    if (ws_size >= need) {
        int* countE  = (int*)d_ws;            // E
        int* countV  = countE + E;            // N
        int* rowptrE = countV + N;            // E+1
        int* rowptrV = rowptrE + E + 1;       // N+1
        int* cursorE = rowptrV + N + 1;       // E
        int* cursorV = cursorE + E;           // N
        int* partE   = cursorV + N;           // 64
        int* partV   = partE + 64;            // 64
        int* adjE    = partV + 64;            // NNZ
        int* adjV    = adjE + NNZ;            // NNZ

        const int nbE = (E + 4095) / 4096;
        const int nbV = (N + 4095) / 4096;

        hipMemsetAsync(countE, 0, (size_t)(E + N) * sizeof(int), stream);

        k_hist<<<(NNZ + 255) / 256, 256, 0, stream>>>(node_idx, edge_idx,
                                                      countE, countV, NNZ);
        k_chunk_sums<<<nbE, 256, 0, stream>>>(countE, E, partE);
        k_chunk_sums<<<nbV, 256, 0, stream>>>(countV, N, partV);
        k_scan_partials2<<<2, 64, 0, stream>>>(partE, nbE, rowptrE + E,
                                               partV, nbV, rowptrV + N);
        k_scan_chunks<<<nbE, 256, 0, stream>>>(countE, E, partE, rowptrE, cursorE);
        k_scan_chunks<<<nbV, 256, 0, stream>>>(countV, N, partV, rowptrV, cursorV);

        k_fill_sliced<<<2048, 256, 0, stream>>>(node_idx, edge_idx,
                                                cursorE, cursorV,
                                                adjE, adjV, NNZ, E, N);

        k_gather_edge<<<((size_t)E * 32 + 255) / 256, 256, 0, stream>>>(
            vfeat, rowptrE, adjE, eout, E);
        k_gather_node<<<((size_t)N * 32 + 255) / 256, 256, 0, stream>>>(
            eout, degE, rowptrV, adjV, vout, N);
        k_fused_gemm<<<(N + 63) / 64, 256, 0, stream>>>(vout, vfeat0, degV, W,
                                                        alpha, beta, N);
    } else {
        float* cnt = (float*)d_ws;
        hipMemsetAsync(d_out, 0, (size_t)out_size * sizeof(float), stream);
        hipMemsetAsync(cnt, 0, (size_t)E * sizeof(float), stream);
        {
            long long threads = (long long)NNZ * 32;
            int blocks = (int)((threads + 255) / 256);
            k_scatter_edge<<<blocks, 256, 0, stream>>>(vfeat, node_idx, edge_idx,
                                                       eout, cnt, NNZ);
        }
        {
            int blocks = (E * 32 + 255) / 256;
            k_normalize_edge<<<blocks, 256, 0, stream>>>(eout, cnt, E);
        }
        {
            long long threads = (long long)NNZ * 32;
            int blocks = (int)((threads + 255) / 256);
            k_scatter_node<<<blocks, 256, 0, stream>>>(eout, degE, node_idx, edge_idx,
                                                       vout, NNZ);
        }
        k_fused_gemm<<<(N + 63) / 64, 256, 0, stream>>>(vout, vfeat0, degV, W,
                                                        alpha, beta, N);
    }
}

// Round 4
// 420.505 us; speedup vs baseline: 8.3643x; 1.0566x over previous
//
#include <hip/hip_runtime.h>

#define DD 128
#define NSLICE 8
#define CK 32

// ===========================================================================
// CSR build
// ===========================================================================

__global__ __launch_bounds__(256) void k_hist(
    const int* __restrict__ node_idx,
    const int* __restrict__ edge_idx,
    int* __restrict__ countE,
    int* __restrict__ countV,
    int nnz)
{
    int i = blockIdx.x * blockDim.x + threadIdx.x;
    if (i >= nnz) return;
    atomicAdd(&countE[edge_idx[i]], 1);
    atomicAdd(&countV[node_idx[i]], 1);
}

__global__ __launch_bounds__(256) void k_chunk_sums(
    const int* __restrict__ cnt, int L, int* __restrict__ partials)
{
    __shared__ int red[256];
    const int tid = threadIdx.x;
    const int base = blockIdx.x * 4096;
    int s = 0;
    for (int j = tid; j < 4096; j += 256) {
        int i = base + j;
        s += (i < L) ? cnt[i] : 0;
    }
    red[tid] = s;
    __syncthreads();
    for (int off = 128; off > 0; off >>= 1) {
        if (tid < off) red[tid] += red[tid + off];
        __syncthreads();
    }
    if (tid == 0) partials[blockIdx.x] = red[0];
}

__global__ void k_scan_partials2(int* __restrict__ pE, int nbE, int* __restrict__ totE,
                                 int* __restrict__ pV, int nbV, int* __restrict__ totV)
{
    if (threadIdx.x != 0) return;
    int* p = (blockIdx.x == 0) ? pE : pV;
    int  nb = (blockIdx.x == 0) ? nbE : nbV;
    int* tot = (blockIdx.x == 0) ? totE : totV;
    int run = 0;
    for (int b = 0; b < nb; ++b) {
        int t = p[b];
        p[b] = run;
        run += t;
    }
    *tot = run;
}

__global__ __launch_bounds__(256) void k_scan_chunks(
    const int* __restrict__ cnt, int L,
    const int* __restrict__ partials,
    int* __restrict__ rowptr, int* __restrict__ cursor)
{
    __shared__ int tsum[256];
    const int tid = threadIdx.x;
    const int tbase = blockIdx.x * 4096 + tid * 16;
    int loc[16];
    int s = 0;
    #pragma unroll
    for (int k = 0; k < 16; ++k) {
        int i = tbase + k;
        loc[k] = (i < L) ? cnt[i] : 0;
        s += loc[k];
    }
    tsum[tid] = s;
    __syncthreads();
    if (tid == 0) {
        int run = partials[blockIdx.x];
        for (int j = 0; j < 256; ++j) {
            int t = tsum[j];
            tsum[j] = run;
            run += t;
        }
    }
    __syncthreads();
    int run = tsum[tid];
    #pragma unroll
    for (int k = 0; k < 16; ++k) {
        int i = tbase + k;
        if (i < L) { rowptr[i] = run; cursor[i] = run; }
        run += loc[k];
    }
}

// ---- XCD-sliced adjacency fill (kills partial-line write amplification) ---
__global__ __launch_bounds__(256) void k_fill_sliced(
    const int* __restrict__ node_idx,
    const int* __restrict__ edge_idx,
    int* __restrict__ cursorE, int* __restrict__ cursorV,
    int* __restrict__ adjE, int* __restrict__ adjV,
    int nnz, int E, int N)
{
    const int s = blockIdx.x & (NSLICE - 1);
    const int g = blockIdx.x >> 3;
    const int ngroups = gridDim.x >> 3;
    const int eb = (E + NSLICE - 1) / NSLICE;
    const int nb = (N + NSLICE - 1) / NSLICE;
    const int elo = s * eb, ehi = min(E, elo + eb);
    const int nlo = s * nb, nhi = min(N, nlo + nb);

    const int stride = ngroups * 256;
    for (int i = g * 256 + threadIdx.x; i < nnz; i += stride) {
        int n = node_idx[i];
        int e = edge_idx[i];
        if (e >= elo && e < ehi) {
            int p = atomicAdd(&cursorE[e], 1);
            adjE[p] = n;
        }
        if (n >= nlo && n < nhi) {
            int p = atomicAdd(&cursorV[n], 1);
            adjV[p] = e;
        }
    }
}

// ===========================================================================
// Gather stages
// ===========================================================================

// ---- stage 1: efeat_new[e] = mean over incident nodes of vfeat ------------
__global__ __launch_bounds__(256) void k_gather_edge(
    const float* __restrict__ vfeat,
    const int* __restrict__ rowptrE,
    const int* __restrict__ adjE,
    float* __restrict__ efeat,
    int n_edges)
{
    const int gid = (blockIdx.x * blockDim.x + threadIdx.x) >> 5;
    if (gid >= n_edges) return;
    const int lane = threadIdx.x & 31;
    const int beg = rowptrE[gid];
    const int len = rowptrE[gid + 1] - beg;

    const float* vb = vfeat + (size_t)lane * 4;
    float4 c0 = {0,0,0,0}, c1 = {0,0,0,0}, c2 = {0,0,0,0}, c3 = {0,0,0,0};

    int k = 0;
    for (; k + 4 <= len; k += 4) {
        int e0 = adjE[beg + k + 0];
        int e1 = adjE[beg + k + 1];
        int e2 = adjE[beg + k + 2];
        int e3 = adjE[beg + k + 3];
        float4 r0 = *(const float4*)(vb + (size_t)e0 * DD);
        float4 r1 = *(const float4*)(vb + (size_t)e1 * DD);
        float4 r2 = *(const float4*)(vb + (size_t)e2 * DD);
        float4 r3 = *(const float4*)(vb + (size_t)e3 * DD);
        c0.x += r0.x; c0.y += r0.y; c0.z += r0.z; c0.w += r0.w;
        c1.x += r1.x; c1.y += r1.y; c1.z += r1.z; c1.w += r1.w;
        c2.x += r2.x; c2.y += r2.y; c2.z += r2.z; c2.w += r2.w;
        c3.x += r3.x; c3.y += r3.y; c3.z += r3.z; c3.w += r3.w;
    }
    for (; k < len; ++k) {
        int e0 = adjE[beg + k];
        float4 r0 = *(const float4*)(vb + (size_t)e0 * DD);
        c0.x += r0.x; c0.y += r0.y; c0.z += r0.z; c0.w += r0.w;
    }
    float inv = (len > 0) ? 1.0f / (float)len : 0.0f;
    float4 o;
    o.x = (c0.x + c1.x + c2.x + c3.x) * inv;
    o.y = (c0.y + c1.y + c2.y + c3.y) * inv;
    o.z = (c0.z + c1.z + c2.z + c3.z) * inv;
    o.w = (c0.w + c1.w + c2.w + c3.w) * inv;
    *(float4*)(efeat + (size_t)gid * DD + lane * 4) = o;
}

// ---- stage 2 fused: vi[n] = (1-a)*degV[n]*sum(degE[e]*efeat[e]) + a*vfeat0[n]
__global__ __launch_bounds__(256) void k_gather_node_vi(
    const float* __restrict__ efeat,
    const float* __restrict__ degE,
    const float* __restrict__ degV,
    const float* __restrict__ vfeat0,
    const float* __restrict__ alpha,
    const int* __restrict__ rowptrV,
    const int* __restrict__ adjV,
    float* __restrict__ vi,
    int n_nodes)
{
    const int gid = (blockIdx.x * blockDim.x + threadIdx.x) >> 5;
    if (gid >= n_nodes) return;
    const int lane = threadIdx.x & 31;
    const int beg = rowptrV[gid];
    const int len = rowptrV[gid + 1] - beg;

    const float* eb = efeat + (size_t)lane * 4;
    float4 c0 = {0,0,0,0}, c1 = {0,0,0,0}, c2 = {0,0,0,0}, c3 = {0,0,0,0};

    int k = 0;
    for (; k + 4 <= len; k += 4) {
        int e0 = adjV[beg + k + 0];
        int e1 = adjV[beg + k + 1];
        int e2 = adjV[beg + k + 2];
        int e3 = adjV[beg + k + 3];
        float w0 = degE[e0], w1 = degE[e1], w2 = degE[e2], w3 = degE[e3];
        float4 r0 = *(const float4*)(eb + (size_t)e0 * DD);
        float4 r1 = *(const float4*)(eb + (size_t)e1 * DD);
        float4 r2 = *(const float4*)(eb + (size_t)e2 * DD);
        float4 r3 = *(const float4*)(eb + (size_t)e3 * DD);
        c0.x += w0 * r0.x; c0.y += w0 * r0.y; c0.z += w0 * r0.z; c0.w += w0 * r0.w;
        c1.x += w1 * r1.x; c1.y += w1 * r1.y; c1.z += w1 * r1.z; c1.w += w1 * r1.w;
        c2.x += w2 * r2.x; c2.y += w2 * r2.y; c2.z += w2 * r2.z; c2.w += w2 * r2.w;
        c3.x += w3 * r3.x; c3.y += w3 * r3.y; c3.z += w3 * r3.z; c3.w += w3 * r3.w;
    }
    for (; k < len; ++k) {
        int e0 = adjV[beg + k];
        float w0 = degE[e0];
        float4 r0 = *(const float4*)(eb + (size_t)e0 * DD);
        c0.x += w0 * r0.x; c0.y += w0 * r0.y; c0.z += w0 * r0.z; c0.w += w0 * r0.w;
    }
    const float a = alpha[0];
    const float s = (1.0f - a) * degV[gid];
    const float4 f = *(const float4*)(vfeat0 + (size_t)gid * DD + lane * 4);
    float4 o;
    o.x = s * (c0.x + c1.x + c2.x + c3.x) + a * f.x;
    o.y = s * (c0.y + c1.y + c2.y + c3.y) + a * f.y;
    o.z = s * (c0.z + c1.z + c2.z + c3.z) + a * f.z;
    o.w = s * (c0.w + c1.w + c2.w + c3.w) + a * f.w;
    *(float4*)(vi + (size_t)gid * DD + lane * 4) = o;
}

// ---------------------------------------------------------------------------
// K-chunked, double-buffered epilogue GEMM, in place on vout (vi -> v):
//   v[n][d] = (1-b) * vi[n][d] + b * sum_k vi[n][k] * W[d][k]
// LDS = 2*18KB (W chunk, padded) + 2*8KB (A chunk, broadcast reads) = 52 KB
// -> 3 blocks/CU (12 waves) vs 1 block (4 waves) for the monolithic version.
// In-place safety: all global reads of the tile's vi rows (chunk staging)
// complete before the final barrier; epilogue re-reads vi[n][c] and writes
// v[n][c] from the same thread (read-before-write per element, tile-local).
// ---------------------------------------------------------------------------
__global__ __launch_bounds__(256) void k_gemm_vi(
    float* __restrict__ vout,           // in: vi, out: v   [N][128]
    const float* __restrict__ W,        // [128][128]
    const float* __restrict__ beta,
    int n_nodes)
{
    __shared__ float Wc[2][128][CK + 4];
    __shared__ float Ac[2][64][CK];

    const int tid = threadIdx.x;
    const float b = beta[0];
    const int nb = blockIdx.x * 64;

    const int tx = tid & 31;
    const int ty = tid >> 5;

    float acc[8][4];
    #pragma unroll
    for (int i = 0; i < 8; ++i)
        #pragma unroll
        for (int j = 0; j < 4; ++j) acc[i][j] = 0.0f;

    // ---- staging helpers (as lambdas over tid) ----
    auto stage = [&](int chunk, int buf) {
        const int kb = chunk * CK;
        // W: 128 rows x 8 float4 = 1024 loads, 4 per thread
        #pragma unroll
        for (int p = 0; p < 4; ++p) {
            int idx = tid + p * 256;
            int row = idx >> 3;
            int l4 = (idx & 7) << 2;
            *(float4*)&Wc[buf][row][l4] = *(const float4*)(W + row * DD + kb + l4);
        }
        // A: 64 rows x 8 float4 = 512 loads, 2 per thread
        #pragma unroll
        for (int p = 0; p < 2; ++p) {
            int idx = tid + p * 256;
            int row = idx >> 3;
            int l4 = (idx & 7) << 2;
            int n = nb + row;
            float4 v = {0, 0, 0, 0};
            if (n < n_nodes) v = *(const float4*)(vout + (size_t)n * DD + kb + l4);
            *(float4*)&Ac[buf][row][l4] = v;
        }
    };

    stage(0, 0);
    __syncthreads();

    const int NCHUNK = DD / CK;   // 4
    for (int c = 0; c < NCHUNK; ++c) {
        if (c + 1 < NCHUNK) stage(c + 1, (c + 1) & 1);
        const int buf = c & 1;
        #pragma unroll
        for (int kc = 0; kc < CK / 4; ++kc) {
            const int k4 = kc << 2;
            float4 af[8];
            #pragma unroll
            for (int i = 0; i < 8; ++i) af[i] = *(const float4*)&Ac[buf][ty * 8 + i][k4];
            float4 bf[4];
            #pragma unroll
            for (int j = 0; j < 4; ++j) bf[j] = *(const float4*)&Wc[buf][tx + 32 * j][k4];
            #pragma unroll
            for (int i = 0; i < 8; ++i) {
                #pragma unroll
                for (int j = 0; j < 4; ++j) {
                    acc[i][j] += af[i].x * bf[j].x;
                    acc[i][j] += af[i].y * bf[j].y;
                    acc[i][j] += af[i].z * bf[j].z;
                    acc[i][j] += af[i].w * bf[j].w;
                }
            }
        }
        __syncthreads();
    }

    // ---- epilogue: v = (1-b)*vi + b*acc ----
    const float omb = 1.0f - b;
    #pragma unroll
    for (int i = 0; i < 8; ++i) {
        int n = nb + ty * 8 + i;
        if (n < n_nodes) {
            #pragma unroll
            for (int j = 0; j < 4; ++j) {
                int cidx = tx + 32 * j;
                float viv = vout[(size_t)n * DD + cidx];
                vout[(size_t)n * DD + cidx] = omb * viv + b * acc[i][j];
            }
        }
    }
}

// ===========================================================================
// Fallback atomic-scatter path (used only if ws_size too small)
// ===========================================================================
__global__ __launch_bounds__(256) void k_scatter_edge(
    const float* __restrict__ vfeat, const int* __restrict__ node_idx,
    const int* __restrict__ edge_idx, float* __restrict__ esum,
    float* __restrict__ cnt, int nnz)
{
    int t = blockIdx.x * blockDim.x + threadIdx.x;
    int i = t >> 5;
    if (i >= nnz) return;
    int c = (t & 31) << 2;
    int n = node_idx[i];
    int e = edge_idx[i];
    const float4 v = *(const float4*)(vfeat + (size_t)n * DD + c);
    float* dst = esum + (size_t)e * DD + c;
    atomicAdd(dst + 0, v.x); atomicAdd(dst + 1, v.y);
    atomicAdd(dst + 2, v.z); atomicAdd(dst + 3, v.w);
    if ((t & 31) == 0) atomicAdd(cnt + e, 1.0f);
}

__global__ __launch_bounds__(256) void k_normalize_edge(
    float* __restrict__ efeat, const float* __restrict__ cnt, int n_edges)
{
    int t = blockIdx.x * blockDim.x + threadIdx.x;
    int e = t >> 5;
    if (e >= n_edges) return;
    int c = (t & 31) << 2;
    float inv = 1.0f / fmaxf(cnt[e], 1.0f);
    float4* p = (float4*)(efeat + (size_t)e * DD + c);
    float4 v = *p;
    v.x *= inv; v.y *= inv; v.z *= inv; v.w *= inv;
    *p = v;
}

__global__ __launch_bounds__(256) void k_scatter_node_vi(
    const float* __restrict__ efeat_new, const float* __restrict__ degE,
    const int* __restrict__ node_idx, const int* __restrict__ edge_idx,
    float* __restrict__ h, int nnz)
{
    int t = blockIdx.x * blockDim.x + threadIdx.x;
    int i = t >> 5;
    if (i >= nnz) return;
    int c = (t & 31) << 2;
    int n = node_idx[i];
    int e = edge_idx[i];
    float w = degE[e];
    const float4 v = *(const float4*)(efeat_new + (size_t)e * DD + c);
    float* dst = h + (size_t)n * DD + c;
    atomicAdd(dst + 0, w * v.x); atomicAdd(dst + 1, w * v.y);
    atomicAdd(dst + 2, w * v.z); atomicAdd(dst + 3, w * v.w);
}

// h -> vi elementwise (fallback path only)
__global__ __launch_bounds__(256) void k_h_to_vi(
    float* __restrict__ h, const float* __restrict__ degV,
    const float* __restrict__ vfeat0, const float* __restrict__ alpha,
    int n_nodes)
{
    int t = blockIdx.x * blockDim.x + threadIdx.x;
    int n = t >> 5;
    if (n >= n_nodes) return;
    int c = (t & 31) << 2;
    float a = alpha[0];
    float s = (1.0f - a) * degV[n];
    float4* p = (float4*)(h + (size_t)n * DD + c);
    const float4 f = *(const float4*)(vfeat0 + (size_t)n * DD + c);
    float4 v = *p;
    v.x = s * v.x + a * f.x;
    v.y = s * v.y + a * f.y;
    v.z = s * v.z + a * f.z;
    v.w = s * v.w + a * f.w;
    *p = v;
}

// ===========================================================================
extern "C" void kernel_launch(void* const* d_in, const int* in_sizes, int n_in,
                              void* d_out, int out_size, void* d_ws, size_t ws_size,
                              hipStream_t stream)
{
    const float* vfeat  = (const float*)d_in[0];
    const float* degE   = (const float*)d_in[2];
    const float* degV   = (const float*)d_in[3];
    const float* vfeat0 = (const float*)d_in[4];
    const float* W      = (const float*)d_in[5];
    const float* alpha  = (const float*)d_in[6];
    const float* beta   = (const float*)d_in[7];
    const int* node_idx = (const int*)d_in[8];
    const int* edge_idx = (const int*)d_in[9];

    const int E   = in_sizes[2];
    const int N   = in_sizes[3];
    const int NNZ = in_sizes[8];

    float* vout = (float*)d_out;                   // [N][128]
    float* eout = (float*)d_out + (size_t)N * DD;  // [E][128]

    const size_t need = ((size_t)3 * E + 3 * N + 2 * (size_t)NNZ + 130) * sizeof(int);

    if (ws_size >= need) {
        int* countE  = (int*)d_ws;            // E
        int* countV  = countE + E;            // N
        int* rowptrE = countV + N;            // E+1
        int* rowptrV = rowptrE + E + 1;       // N+1
        int* cursorE = rowptrV + N + 1;       // E
        int* cursorV = cursorE + E;           // N
        int* partE   = cursorV + N;           // 64
        int* partV   = partE + 64;            // 64
        int* adjE    = partV + 64;            // NNZ
        int* adjV    = adjE + NNZ;            // NNZ

        const int nbE = (E + 4095) / 4096;
        const int nbV = (N + 4095) / 4096;

        hipMemsetAsync(countE, 0, (size_t)(E + N) * sizeof(int), stream);

        k_hist<<<(NNZ + 255) / 256, 256, 0, stream>>>(node_idx, edge_idx,
                                                      countE, countV, NNZ);
        k_chunk_sums<<<nbE, 256, 0, stream>>>(countE, E, partE);
        k_chunk_sums<<<nbV, 256, 0, stream>>>(countV, N, partV);
        k_scan_partials2<<<2, 64, 0, stream>>>(partE, nbE, rowptrE + E,
                                               partV, nbV, rowptrV + N);
        k_scan_chunks<<<nbE, 256, 0, stream>>>(countE, E, partE, rowptrE, cursorE);
        k_scan_chunks<<<nbV, 256, 0, stream>>>(countV, N, partV, rowptrV, cursorV);

        k_fill_sliced<<<2048, 256, 0, stream>>>(node_idx, edge_idx,
                                                cursorE, cursorV,
                                                adjE, adjV, NNZ, E, N);

        k_gather_edge<<<((size_t)E * 32 + 255) / 256, 256, 0, stream>>>(
            vfeat, rowptrE, adjE, eout, E);
        k_gather_node_vi<<<((size_t)N * 32 + 255) / 256, 256, 0, stream>>>(
            eout, degE, degV, vfeat0, alpha, rowptrV, adjV, vout, N);
        k_gemm_vi<<<(N + 63) / 64, 256, 0, stream>>>(vout, W, beta, N);
    } else {
        float* cnt = (float*)d_ws;
        hipMemsetAsync(d_out, 0, (size_t)out_size * sizeof(float), stream);
        hipMemsetAsync(cnt, 0, (size_t)E * sizeof(float), stream);
        {
            long long threads = (long long)NNZ * 32;
            int blocks = (int)((threads + 255) / 256);
            k_scatter_edge<<<blocks, 256, 0, stream>>>(vfeat, node_idx, edge_idx,
                                                       eout, cnt, NNZ);
        }
        {
            int blocks = (E * 32 + 255) / 256;
            k_normalize_edge<<<blocks, 256, 0, stream>>>(eout, cnt, E);
        }
        {
            long long threads = (long long)NNZ * 32;
            int blocks = (int)((threads + 255) / 256);
            k_scatter_node_vi<<<blocks, 256, 0, stream>>>(eout, degE, node_idx, edge_idx,
                                                          vout, NNZ);
        }
        k_h_to_vi<<<((size_t)N * 32 + 255) / 256, 256, 0, stream>>>(
            vout, degV, vfeat0, alpha, N);
        k_gemm_vi<<<(N + 63) / 64, 256, 0, stream>>>(vout, W, beta, N);
    }
}